// Round 9
// baseline (238.100 us; speedup 1.0000x reference)
//
#include <hip/hip_runtime.h>
#include <hip/hip_bf16.h>
#include <math.h>

#define B 32
#define N 8400
#define M 60
#define C 80
#define KMAX 13
#define INF_COST 1e8f
#define NJ 33   // ceil(N/256)

// ---------- shared math: single producer of cost bits ----------
__device__ __forceinline__ float iou_fn(
    float px1, float py1, float px2, float py2,
    float gx1, float gy1, float gx2, float gy2)
{
#pragma clang fp contract(off)
    float ltx = fmaxf(px1, gx1), lty = fmaxf(py1, gy1);
    float rbx = fminf(px2, gx2), rby = fminf(py2, gy2);
    float wx = fmaxf(rbx - ltx, 0.0f), wy = fmaxf(rby - lty, 0.0f);
    float inter = wx * wy;
    float a1 = (px2 - px1) * (py2 - py1);
    float a2 = (gx2 - gx1) * (gy2 - gy1);
    float uni = fmaxf(a1 + a2 - inter, 1e-6f);
    return inter / uni;
}

__device__ __forceinline__ float cost_fn(
    float iou, float logit,
    float pcx, float pcy, float stride,
    float gcx, float gcy)
{
#pragma clang fp contract(off)
    float dx = pcx - gcx, dy = pcy - gcy;
    float dist = sqrtf(dx * dx + dy * dy) / stride;
    float soft = exp10f(dist - 3.0f);
    float iouc = -logf(iou + 1e-7f) * 3.0f;
    float sig = 1.0f / (1.0f + expf(-logit));
    float scale = iou - sig;
    float sc2 = scale * scale;
    float bce = fmaxf(logit, 0.0f) - logit * iou + log1pf(expf(-fabsf(logit)));
    float cls = bce * sc2;
    return (cls + iouc) + soft;
}

// ---------- kernel 1: valid_mask[b,n] ----------
__global__ __launch_bounds__(256) void k_valid(
    const float* __restrict__ priors,
    const float* __restrict__ gt_bboxes,
    const float* __restrict__ pad,
    unsigned char* __restrict__ valid)
{
    int idx = blockIdx.x * 256 + threadIdx.x;
    if (idx >= B * N) return;
    int b = idx / N, n = idx % N;
    float px = priors[n * 4 + 0];
    float py = priors[n * 4 + 1];
    const float* g = gt_bboxes + (size_t)b * M * 4;
    const float* pf = pad + (size_t)b * M;
    unsigned char v = 0;
    for (int m = 0; m < M; m++) {
        float x1 = g[m * 4 + 0], y1 = g[m * 4 + 1];
        float x2 = g[m * 4 + 2], y2 = g[m * 4 + 3];
        float mn = fminf(fminf(px - x1, py - y1), fminf(x2 - px, y2 - py));
        if (mn > 0.0f && pf[m] > 0.0f) { v = 1; break; }
    }
    valid[idx] = v;
}

// ---------- kernel 1b: transpose + COST: t[b][m][n] = cost(b,n,m) ----------
// grid 4224 = 8 XCD * 528; per block: one (b, 64-n tile), all m
__global__ __launch_bounds__(256) void k_cost(
    const float* __restrict__ scores,
    const int*   __restrict__ labels,
    const float* __restrict__ pred_bboxes,
    const float* __restrict__ priors,
    const float* __restrict__ gt_bboxes,
    const unsigned char* __restrict__ valid,
    float* __restrict__ t)
{
    __shared__ float s_t[80][65];     // transposed scores tile (20.8 KB)
    __shared__ float s_g[M][6];       // gx1,gy1,gx2,gy2,gcx,gcy
    __shared__ int   s_lab[M];

    const int i = blockIdx.x;
    const int cidx = (i & 7) * 528 + (i >> 3);
    const int b = cidx / 132;
    const int tile = cidx % 132;
    const int n0 = tile * 64;
    const int lim = (N - n0 < 64) ? (N - n0) : 64;

    if (threadIdx.x < M) {
        int m = threadIdx.x, gi = b * M + m;
        float4 g = ((const float4*)gt_bboxes)[gi];
        s_g[m][0] = g.x; s_g[m][1] = g.y; s_g[m][2] = g.z; s_g[m][3] = g.w;
        s_g[m][4] = (g.x + g.z) * 0.5f;
        s_g[m][5] = (g.y + g.w) * 0.5f;
        s_lab[m] = labels[gi];
    }

    const float4* src4 = (const float4*)(scores + ((size_t)b * N + n0) * C);
    for (int idx = threadIdx.x; idx < lim * 20; idx += 256) {
        int r = idx / 20, qq = idx % 20;
        float4 v = src4[r * 20 + qq];
        s_t[4 * qq + 0][r] = v.x;
        s_t[4 * qq + 1][r] = v.y;
        s_t[4 * qq + 2][r] = v.z;
        s_t[4 * qq + 3][r] = v.w;
    }
    __syncthreads();

    const int q = threadIdx.x & 15;           // this thread's fixed n-quad
    if (4 * q >= lim) return;                 // (no barriers after this point)

    const size_t nb = (size_t)b * N + n0 + 4 * q;
    const float4* pbx = (const float4*)pred_bboxes;
    const float4* prx = (const float4*)priors;
    float4 P0 = pbx[nb + 0], P1 = pbx[nb + 1], P2 = pbx[nb + 2], P3 = pbx[nb + 3];
    float4 R0 = prx[n0 + 4 * q + 0], R1 = prx[n0 + 4 * q + 1];
    float4 R2 = prx[n0 + 4 * q + 2], R3 = prx[n0 + 4 * q + 3];
    const unsigned char* vr = valid + nb;
    bool V0 = vr[0], V1 = vr[1], V2 = vr[2], V3 = vr[3];

    float* trow = t + (size_t)b * M * N + n0 + 4 * q;
    for (int m = threadIdx.x >> 4; m < M; m += 16) {
        float gx1 = s_g[m][0], gy1 = s_g[m][1], gx2 = s_g[m][2], gy2 = s_g[m][3];
        float gcx = s_g[m][4], gcy = s_g[m][5];
        int lab = s_lab[m];
        float4 o;
        o.x = V0 ? cost_fn(iou_fn(P0.x, P0.y, P0.z, P0.w, gx1, gy1, gx2, gy2),
                           s_t[lab][4 * q + 0], R0.x, R0.y, R0.z, gcx, gcy) : INF_COST;
        o.y = V1 ? cost_fn(iou_fn(P1.x, P1.y, P1.z, P1.w, gx1, gy1, gx2, gy2),
                           s_t[lab][4 * q + 1], R1.x, R1.y, R1.z, gcx, gcy) : INF_COST;
        o.z = V2 ? cost_fn(iou_fn(P2.x, P2.y, P2.z, P2.w, gx1, gy1, gx2, gy2),
                           s_t[lab][4 * q + 2], R2.x, R2.y, R2.z, gcx, gcy) : INF_COST;
        o.w = V3 ? cost_fn(iou_fn(P3.x, P3.y, P3.z, P3.w, gx1, gy1, gx2, gy2),
                           s_t[lab][4 * q + 3], R3.x, R3.y, R3.z, gcx, gcy) : INF_COST;
        *(float4*)(trow + (size_t)m * N) = o;
    }
}

// ---------- radix helpers ----------
__device__ __forceinline__ void hist_zero(unsigned (*s_h)[257], int tid) {
    unsigned* f = &s_h[0][0];
    for (int j = tid; j < 4 * 257; j += 256) f[j] = 0;
}

// prefix over 256 bins (+ optional virtual bin); s_sel[2]=total; if need: s_sel[0]=bin, s_sel[1]=count below
__device__ __forceinline__ void hist_pick(unsigned (*s_h)[257], unsigned* s_wsum,
    unsigned* s_sel, int tid, int lane, int w, unsigned need, int infbin, unsigned infcnt)
{
    unsigned cnt = s_h[0][tid] + s_h[1][tid] + s_h[2][tid] + s_h[3][tid];
    if (tid == infbin) cnt += infcnt;
    unsigned x = cnt;
#pragma unroll
    for (int d = 1; d < 64; d <<= 1) {
        unsigned y = (unsigned)__shfl_up((int)x, d);
        if (lane >= d) x += y;
    }
    if (lane == 63) s_wsum[w] = x;
    __syncthreads();
    unsigned off = 0;
    for (int ww = 0; ww < w; ++ww) off += s_wsum[ww];
    unsigned incl = x + off;
    unsigned excl = incl - cnt;
    if (tid == 255) s_sel[2] = incl;
    if (need != 0u && excl < need && need <= incl) { s_sel[0] = (unsigned)tid; s_sel[1] = excl; }
    __syncthreads();
}

// ---------- kernel 2: selection only (register-resident values) ----------
__global__ __launch_bounds__(256) void k_select(
    const float* __restrict__ pred_bboxes,
    const float* __restrict__ pred_scores,
    const float* __restrict__ tsc,           // cost matrix (use_t) from k_cost
    const float* __restrict__ priors,
    const int*   __restrict__ gt_labels,
    const float* __restrict__ gt_bboxes,
    const float* __restrict__ pad,
    const unsigned char* __restrict__ valid,
    float* __restrict__ cK, int* __restrict__ nK,
    int use_t)
{
    __shared__ float    s_val[N];        // cost column for the tie-rank scan
    __shared__ unsigned s_h[4][257];     // bank-spread histogram copies
    __shared__ unsigned s_wsum[4];
    __shared__ unsigned s_sel[4];
    __shared__ float    s_coll[16];
    __shared__ unsigned s_cnt;
    __shared__ unsigned s_infcnt;

    const int i = blockIdx.x;
    const int bm = (i & 7) * 240 + (i >> 3);
    if (pad[bm] == 0.0f) return;         // padded GT: cK/nK never consumed

    const int b = bm / M;
    const int tid = threadIdx.x;
    const int lane = tid & 63;
    const int w = tid >> 6;

    const float4 g = ((const float4*)gt_bboxes)[bm];
    const float gx1 = g.x, gy1 = g.y, gx2 = g.z, gy2 = g.w;
    const float gcx = (gx1 + gx2) * 0.5f, gcy = (gy1 + gy2) * 0.5f;
    const int label = gt_labels[bm];
    const float4* pb4 = ((const float4*)pred_bboxes) + (size_t)b * N;

    float myv[NJ];

    // ======== pass A: iou into registers + level-0 histogram (positives only) ========
    hist_zero(s_h, tid);
    if (tid == 0) s_cnt = 0;
    __syncthreads();
#pragma unroll
    for (int j = 0; j < NJ; ++j) {
        int n = tid + (j << 8);
        float v = 0.0f;
        if (n < N) {
            float4 p = pb4[n];
            v = iou_fn(p.x, p.y, p.z, p.w, gx1, gy1, gx2, gy2);
            unsigned bits = __float_as_uint(v);
            if (bits) atomicAdd(&s_h[tid & 3][bits >> 24], 1u);
        }
        myv[j] = v;
    }
    __syncthreads();

    hist_pick(s_h, s_wsum, s_sel, tid, lane, w, 0u, -1, 0u);
    const unsigned total = s_sel[2];
    unsigned thr_i = 0;
    if (total >= 13u) {
        unsigned pref = 0, mask = 0, need = total - 12u;  // asc rank of 13th-largest
        for (int lev = 0; lev < 4; ++lev) {
            int shift = 24 - 8 * lev;
            if (lev) {
                hist_zero(s_h, tid);
                __syncthreads();
#pragma unroll
                for (int j = 0; j < NJ; ++j) {
                    unsigned bits = __float_as_uint(myv[j]);
                    if (bits && (bits & mask) == pref)
                        atomicAdd(&s_h[tid & 3][(bits >> shift) & 255u], 1u);
                }
                __syncthreads();
            }
            hist_pick(s_h, s_wsum, s_sel, tid, lane, w, need, -1, 0u);
            pref |= s_sel[0] << shift;
            mask |= 0xFFu << shift;
            need -= s_sel[1];
        }
        thr_i = pref;                                     // exact 13th-largest bits
    }
#pragma unroll
    for (int j = 0; j < NJ; ++j) {
        unsigned bits = __float_as_uint(myv[j]);
        if (bits > thr_i) {
            unsigned p = atomicAdd(&s_cnt, 1u);
            if (p < 16u) s_coll[p] = myv[j];              // <=12 strictly-greater items
        }
    }
    __syncthreads();
    if (tid == 0) {
        int cg = (int)s_cnt; if (cg > 13) cg = 13;
        for (int a = 1; a < cg; ++a) {                    // desc sort (<=12)
            float key = s_coll[a]; int bp = a - 1;
            while (bp >= 0 && s_coll[bp] < key) { s_coll[bp + 1] = s_coll[bp]; --bp; }
            s_coll[bp + 1] = key;
        }
        float ss = 0.0f;
        for (int a = 0; a < cg; ++a) ss += s_coll[a];     // descending-order sum
        if (total >= 13u) {
            float thr = __uint_as_float(thr_i);
            for (int a = cg; a < 13; ++a) ss += thr;      // tied values fill to 13
        }
        int KK = (int)ss;                                 // trunc == astype(int32)
        if (KK < 1) KK = 1;
        s_sel[3] = (unsigned)KK;
    }

    // ======== pass B: cost into registers+LDS; exact-INF excluded from hists ========
    hist_zero(s_h, tid);
    if (tid == 0) s_infcnt = 0;
    __syncthreads();
    const unsigned INFB = __float_as_uint(INF_COST);
    const float* tcol = tsc + (size_t)bm * N;
    const float* srow = pred_scores + (size_t)b * N * C;
    const unsigned char* vrow = valid + (size_t)b * N;
    const float4* pr4 = (const float4*)priors;
    unsigned cInf = 0;
    if (use_t) {
#pragma unroll
        for (int j = 0; j < NJ; ++j) {
            int n = tid + (j << 8);
            float c = 0.0f;
            if (n < N) {
                c = tcol[n];
                s_val[n] = c;
                unsigned bits = __float_as_uint(c);
                if (bits == INFB) cInf++;
                else atomicAdd(&s_h[tid & 3][bits >> 24], 1u);
            }
            myv[j] = c;                                   // OOR -> bits 0: excluded below
        }
    } else {
#pragma unroll
        for (int j = 0; j < NJ; ++j) {
            int n = tid + (j << 8);
            float c = 0.0f;
            if (n < N) {
                if (vrow[n]) {
                    float logit = srow[(size_t)n * C + label];
                    float4 pr = pr4[n];
                    c = cost_fn(myv[j], logit, pr.x, pr.y, pr.z, gcx, gcy);
                } else c = INF_COST;
                s_val[n] = c;
                unsigned bits = __float_as_uint(c);
                if (bits == INFB) cInf++;
                else atomicAdd(&s_h[tid & 3][bits >> 24], 1u);
            }
            myv[j] = c;
        }
    }
#pragma unroll
    for (int d = 1; d < 64; d <<= 1) cInf += (unsigned)__shfl_xor((int)cInf, d);
    if (lane == 0 && cInf) atomicAdd(&s_infcnt, cInf);
    __syncthreads();
    const unsigned nInf = s_infcnt;
    const unsigned K = s_sel[3];

    unsigned pref = 0, mask = 0, need = K;
    for (int lev = 0; lev < 4; ++lev) {
        int shift = 24 - 8 * lev;
        if (lev) {
            hist_zero(s_h, tid);
            __syncthreads();
#pragma unroll
            for (int j = 0; j < NJ; ++j) {
                unsigned bits = __float_as_uint(myv[j]);
                if (bits && bits != INFB && (bits & mask) == pref)
                    atomicAdd(&s_h[tid & 3][(bits >> shift) & 255u], 1u);
            }
            __syncthreads();
        }
        int infbin = ((INFB & mask) == pref) ? (int)((INFB >> shift) & 255u) : -1;
        hist_pick(s_h, s_wsum, s_sel, tid, lane, w, need, infbin, nInf);
        pref |= s_sel[0] << shift;
        mask |= 0xFFu << shift;
        need -= s_sel[1];
    }
    // rank among ties (ascending n): contiguous LDS segments
    {
        const int lo = tid * 33;
        const int hi = (lo + 33 < N) ? (lo + 33) : N;
        unsigned cnt = 0;
        for (int n = lo; n < hi; ++n) cnt += (__float_as_uint(s_val[n]) == pref) ? 1u : 0u;
        unsigned x = cnt;
#pragma unroll
        for (int d = 1; d < 64; d <<= 1) {
            unsigned y = (unsigned)__shfl_up((int)x, d);
            if (lane >= d) x += y;
        }
        if (lane == 63) s_wsum[w] = x;
        __syncthreads();
        unsigned off = 0;
        for (int ww = 0; ww < w; ++ww) off += s_wsum[ww];
        unsigned incl = x + off, excl = incl - cnt;
        if (excl < need && need <= incl) {
            unsigned want = need - excl;
            for (int n = lo; n < hi; ++n) {
                if (__float_as_uint(s_val[n]) == pref) {
                    if (--want == 0u) { s_sel[0] = (unsigned)n; break; }
                }
            }
        }
        __syncthreads();
    }
    if (tid == 0) { cK[bm] = __uint_as_float(pref); nK[bm] = (int)s_sel[0]; }
}

// ---------- kernel 3: per-(b,n) row; reads stored cost column (use_t) ----------
__global__ __launch_bounds__(256) void k_assign(
    const float* __restrict__ pred_bboxes,
    const float* __restrict__ pred_scores,
    const float* __restrict__ tsc,
    const float* __restrict__ priors,
    const int*   __restrict__ gt_labels,
    const float* __restrict__ gt_bboxes,
    const float* __restrict__ pad,
    const unsigned char* __restrict__ valid,
    const float* __restrict__ cK,
    const int*   __restrict__ nK,
    float* __restrict__ out,
    int use_t)
{
    __shared__ float s_box[M][4];
    __shared__ float s_gc[M][2];
    __shared__ float s_ck[M];
    __shared__ int   s_lab[M];
    __shared__ int   s_nk[M];
    __shared__ unsigned char s_gtv[M];

    const int i = blockIdx.x;
    const int cidx = (i & 7) * 132 + (i >> 3);
    const int b = cidx / 33;
    const int chunk = cidx % 33;
    const int n = chunk * 256 + threadIdx.x;

    if (threadIdx.x < M) {
        int m = threadIdx.x, gi = b * M + m;
        float4 g = ((const float4*)gt_bboxes)[gi];
        s_box[m][0] = g.x; s_box[m][1] = g.y; s_box[m][2] = g.z; s_box[m][3] = g.w;
        s_gc[m][0] = (g.x + g.z) * 0.5f;
        s_gc[m][1] = (g.y + g.w) * 0.5f;
        s_ck[m] = cK[gi];
        s_lab[m] = gt_labels[gi];
        s_nk[m] = nK[gi];
        s_gtv[m] = (pad[gi] > 0.0f) ? 1 : 0;
    }
    __syncthreads();
    if (n >= N) return;

    const size_t idx = (size_t)b * N + n;

    int count = 0, firstm = -1;
    float minc = INFINITY; int amin = 0;
    float firstiou = 0.0f, aminiou = 0.0f;

    if (use_t) {
        const float* tb = tsc + (size_t)b * M * N;
#pragma unroll 4
        for (int m = 0; m < M; m++) {
            float c = tb[(size_t)m * N + n];
            if (c < minc) { minc = c; amin = m; }
            float ckm = s_ck[m]; int nkm = s_nk[m];
            bool matched = s_gtv[m] && (c < ckm || (c == ckm && n <= nkm));
            if (matched) { count++; if (firstm < 0) firstm = m; }
        }
        int mstar = (count > 1) ? amin : firstm;
        float mi = 0.0f;
        if (mstar >= 0) {
            float4 p = ((const float4*)pred_bboxes)[idx];
            mi = iou_fn(p.x, p.y, p.z, p.w,
                        s_box[mstar][0], s_box[mstar][1], s_box[mstar][2], s_box[mstar][3]);
        }
        float* o_lab = out;
        float* o_w   = out + (size_t)B * N;
        float* o_box = out + (size_t)2 * B * N;
        float* o_met = out + (size_t)6 * B * N;
        o_w[idx] = 1.0f;
        if (mstar >= 0) {
            o_lab[idx] = (float)s_lab[mstar];
            o_box[idx * 4 + 0] = s_box[mstar][0];
            o_box[idx * 4 + 1] = s_box[mstar][1];
            o_box[idx * 4 + 2] = s_box[mstar][2];
            o_box[idx * 4 + 3] = s_box[mstar][3];
            o_met[idx] = mi;
        } else {
            o_lab[idx] = (float)C;
            o_box[idx * 4 + 0] = 0.0f;
            o_box[idx * 4 + 1] = 0.0f;
            o_box[idx * 4 + 2] = 0.0f;
            o_box[idx * 4 + 3] = 0.0f;
            o_met[idx] = 0.0f;
        }
        return;
    }

    // -------- fallback (use_t == 0) --------
    const float4 p = ((const float4*)pred_bboxes)[idx];
    const float4 pr = ((const float4*)priors)[n];
    const int vn = valid[idx];
    const float* scores = pred_scores + idx * C;

    for (int m = 0; m < M; m++) {
        float iou = iou_fn(p.x, p.y, p.z, p.w,
                           s_box[m][0], s_box[m][1], s_box[m][2], s_box[m][3]);
        float c;
        if (vn) {
            float logit = scores[s_lab[m]];
            c = cost_fn(iou, logit, pr.x, pr.y, pr.z, s_gc[m][0], s_gc[m][1]);
        } else {
            c = INF_COST;
        }
        if (c < minc) { minc = c; amin = m; aminiou = iou; }
        float ckm = s_ck[m]; int nkm = s_nk[m];
        bool matched = s_gtv[m] && (c < ckm || (c == ckm && n <= nkm));
        if (matched) { count++; if (firstm < 0) { firstm = m; firstiou = iou; } }
    }

    int mstar; float mi;
    if (count > 1)       { mstar = amin;   mi = aminiou; }
    else if (count == 1) { mstar = firstm; mi = firstiou; }
    else                 { mstar = -1;     mi = 0.0f; }

    float* o_lab = out;
    float* o_w   = out + (size_t)B * N;
    float* o_box = out + (size_t)2 * B * N;
    float* o_met = out + (size_t)6 * B * N;
    o_w[idx] = 1.0f;
    if (mstar >= 0) {
        o_lab[idx] = (float)s_lab[mstar];
        o_box[idx * 4 + 0] = s_box[mstar][0];
        o_box[idx * 4 + 1] = s_box[mstar][1];
        o_box[idx * 4 + 2] = s_box[mstar][2];
        o_box[idx * 4 + 3] = s_box[mstar][3];
        o_met[idx] = mi;
    } else {
        o_lab[idx] = (float)C;
        o_box[idx * 4 + 0] = 0.0f;
        o_box[idx * 4 + 1] = 0.0f;
        o_box[idx * 4 + 2] = 0.0f;
        o_box[idx * 4 + 3] = 0.0f;
        o_met[idx] = 0.0f;
    }
}

extern "C" void kernel_launch(void* const* d_in, const int* in_sizes, int n_in,
                              void* d_out, int out_size, void* d_ws, size_t ws_size,
                              hipStream_t stream) {
    const float* pred_bboxes = (const float*)d_in[0];
    const float* pred_scores = (const float*)d_in[1];
    const float* priors      = (const float*)d_in[2];
    const int*   gt_labels   = (const int*)d_in[3];
    const float* gt_bboxes   = (const float*)d_in[4];
    const float* pad         = (const float*)d_in[5];
    float* out = (float*)d_out;

    const size_t t_bytes = (size_t)B * M * N * sizeof(float);
    const size_t need = t_bytes + (size_t)B * N + (size_t)B * M * 8;
    const int use_t = (ws_size >= need) ? 1 : 0;

    unsigned char* ws = (unsigned char*)d_ws;
    float* tsc; unsigned char* valid; float* cKp; int* nKp;
    if (use_t) {
        tsc   = (float*)ws;
        valid = ws + t_bytes;
        cKp   = (float*)(ws + t_bytes + (size_t)B * N);
        nKp   = (int*)  (ws + t_bytes + (size_t)B * N + (size_t)B * M * 4);
    } else {
        tsc   = (float*)ws;   // never dereferenced
        valid = ws;
        cKp   = (float*)(ws + (size_t)B * N);
        nKp   = (int*)  (ws + (size_t)B * N + (size_t)B * M * 4);
    }

    k_valid<<<(B * N + 255) / 256, 256, 0, stream>>>(priors, gt_bboxes, pad, valid);
    if (use_t)
        k_cost<<<B * 132, 256, 0, stream>>>(pred_scores, gt_labels, pred_bboxes, priors,
                                            gt_bboxes, valid, tsc);
    k_select<<<B * M, 256, 0, stream>>>(pred_bboxes, pred_scores, tsc, priors, gt_labels,
                                        gt_bboxes, pad, valid, cKp, nKp, use_t);
    k_assign<<<33 * B, 256, 0, stream>>>(pred_bboxes, pred_scores, tsc, priors, gt_labels,
                                         gt_bboxes, pad, valid, cKp, nKp, out, use_t);
}

// Round 10
// 172.838 us; speedup vs baseline: 1.3776x; 1.3776x over previous
//
#include <hip/hip_runtime.h>
#include <hip/hip_bf16.h>
#include <math.h>

#define B 32
#define N 8400
#define M 60
#define C 80
#define KMAX 13
#define INF_COST 1e8f
#define NJ 33   // ceil(N/256)

// ---------- iou: bit-exact IEEE (feeds dynamic_ks sum + metric output) ----------
__device__ __forceinline__ float iou_fn(
    float px1, float py1, float px2, float py2,
    float gx1, float gy1, float gx2, float gy2)
{
#pragma clang fp contract(off)
    float ltx = fmaxf(px1, gx1), lty = fmaxf(py1, gy1);
    float rbx = fminf(px2, gx2), rby = fminf(py2, gy2);
    float wx = fmaxf(rbx - ltx, 0.0f), wy = fmaxf(rby - lty, 0.0f);
    float inter = wx * wy;
    float a1 = (px2 - px1) * (py2 - py1);
    float a2 = (gx2 - gx1) * (gy2 - gy1);
    float uni = fmaxf(a1 + a2 - inter, 1e-6f);
    return inter / uni;
}

// ---------- cost: fast hardware transcendentals (single producer of cost bits;
// accuracy ~1e-6 rel, selection margins ~1e-2 — internal consistency via stored matrix) ----------
__device__ __forceinline__ float cost_fast(
    float iou, float logit,
    float pcx, float pcy, float rstride,   // rstride = 1/stride (exact: pow2)
    float gcx, float gcy)
{
    const float LOG2_10 = 3.3219280948873623f;
    const float LOG2_E  = 1.4426950408889634f;
    const float LN_2    = 0.6931471805599453f;
    float dx = pcx - gcx, dy = pcy - gcy;
    float dist = __builtin_amdgcn_sqrtf(dx * dx + dy * dy) * rstride;
    float soft = __builtin_amdgcn_exp2f((dist - 3.0f) * LOG2_10);
    float iouc = __builtin_amdgcn_logf(iou + 1e-7f) * (-3.0f * LN_2);
    float e    = __builtin_amdgcn_exp2f(-logit * LOG2_E);
    float sig  = __builtin_amdgcn_rcpf(1.0f + e);
    float t    = __builtin_amdgcn_exp2f(-fabsf(logit) * LOG2_E);
    float sp   = __builtin_amdgcn_logf(1.0f + t) * LN_2;
    float bce  = fmaxf(logit, 0.0f) - logit * iou + sp;
    float scale = iou - sig;
    float cls  = bce * scale * scale;
    return (cls + iouc) + soft;
}

// ---------- kernel 1: valid_mask[b,n] ----------
__global__ __launch_bounds__(256) void k_valid(
    const float* __restrict__ priors,
    const float* __restrict__ gt_bboxes,
    const float* __restrict__ pad,
    unsigned char* __restrict__ valid)
{
    int idx = blockIdx.x * 256 + threadIdx.x;
    if (idx >= B * N) return;
    int b = idx / N, n = idx % N;
    float px = priors[n * 4 + 0];
    float py = priors[n * 4 + 1];
    const float* g = gt_bboxes + (size_t)b * M * 4;
    const float* pf = pad + (size_t)b * M;
    unsigned char v = 0;
    for (int m = 0; m < M; m++) {
        float x1 = g[m * 4 + 0], y1 = g[m * 4 + 1];
        float x2 = g[m * 4 + 2], y2 = g[m * 4 + 3];
        float mn = fminf(fminf(px - x1, py - y1), fminf(x2 - px, y2 - py));
        if (mn > 0.0f && pf[m] > 0.0f) { v = 1; break; }
    }
    valid[idx] = v;
}

// ---------- kernel 1b: transpose + COST: t[b][m][n] = cost(b,n,m) ----------
__global__ __launch_bounds__(256) void k_cost(
    const float* __restrict__ scores,
    const int*   __restrict__ labels,
    const float* __restrict__ pred_bboxes,
    const float* __restrict__ priors,
    const float* __restrict__ gt_bboxes,
    const unsigned char* __restrict__ valid,
    float* __restrict__ t)
{
    __shared__ float s_t[80][65];     // transposed scores tile
    __shared__ float s_g[M][6];       // gx1,gy1,gx2,gy2,gcx,gcy
    __shared__ int   s_lab[M];

    const int cidx = blockIdx.x;      // plain: round-robin spreads uneven work
    const int b = cidx / 132;
    const int tile = cidx % 132;
    const int n0 = tile * 64;
    const int lim = (N - n0 < 64) ? (N - n0) : 64;

    if (threadIdx.x < M) {
        int m = threadIdx.x, gi = b * M + m;
        float4 g = ((const float4*)gt_bboxes)[gi];
        s_g[m][0] = g.x; s_g[m][1] = g.y; s_g[m][2] = g.z; s_g[m][3] = g.w;
        s_g[m][4] = (g.x + g.z) * 0.5f;
        s_g[m][5] = (g.y + g.w) * 0.5f;
        s_lab[m] = labels[gi];
    }

    const float4* src4 = (const float4*)(scores + ((size_t)b * N + n0) * C);
    for (int idx = threadIdx.x; idx < lim * 20; idx += 256) {
        int r = idx / 20, qq = idx % 20;
        float4 v = src4[r * 20 + qq];
        s_t[4 * qq + 0][r] = v.x;
        s_t[4 * qq + 1][r] = v.y;
        s_t[4 * qq + 2][r] = v.z;
        s_t[4 * qq + 3][r] = v.w;
    }
    __syncthreads();

    const int q = threadIdx.x & 15;
    if (4 * q >= lim) return;          // no barriers after this point

    const size_t nb = (size_t)b * N + n0 + 4 * q;
    const unsigned char* vr = valid + nb;
    bool V0 = vr[0], V1 = vr[1], V2 = vr[2], V3 = vr[3];
    float* trow = t + (size_t)b * M * N + n0 + 4 * q;

    if (!(V0 | V1 | V2 | V3)) {        // whole-quad invalid: INF rows, no math
        float4 o = make_float4(INF_COST, INF_COST, INF_COST, INF_COST);
        for (int m = threadIdx.x >> 4; m < M; m += 16)
            *(float4*)(trow + (size_t)m * N) = o;
        return;
    }

    const float4* pbx = (const float4*)pred_bboxes;
    const float4* prx = (const float4*)priors;
    float4 P0 = pbx[nb + 0], P1 = pbx[nb + 1], P2 = pbx[nb + 2], P3 = pbx[nb + 3];
    float4 R0 = prx[n0 + 4 * q + 0], R1 = prx[n0 + 4 * q + 1];
    float4 R2 = prx[n0 + 4 * q + 2], R3 = prx[n0 + 4 * q + 3];
    float rs0 = __builtin_amdgcn_rcpf(R0.z);   // exact: strides are pow2
    float rs1 = __builtin_amdgcn_rcpf(R1.z);
    float rs2 = __builtin_amdgcn_rcpf(R2.z);
    float rs3 = __builtin_amdgcn_rcpf(R3.z);

    for (int m = threadIdx.x >> 4; m < M; m += 16) {
        float gx1 = s_g[m][0], gy1 = s_g[m][1], gx2 = s_g[m][2], gy2 = s_g[m][3];
        float gcx = s_g[m][4], gcy = s_g[m][5];
        int lab = s_lab[m];
        float4 o;
        o.x = V0 ? cost_fast(iou_fn(P0.x, P0.y, P0.z, P0.w, gx1, gy1, gx2, gy2),
                             s_t[lab][4 * q + 0], R0.x, R0.y, rs0, gcx, gcy) : INF_COST;
        o.y = V1 ? cost_fast(iou_fn(P1.x, P1.y, P1.z, P1.w, gx1, gy1, gx2, gy2),
                             s_t[lab][4 * q + 1], R1.x, R1.y, rs1, gcx, gcy) : INF_COST;
        o.z = V2 ? cost_fast(iou_fn(P2.x, P2.y, P2.z, P2.w, gx1, gy1, gx2, gy2),
                             s_t[lab][4 * q + 2], R2.x, R2.y, rs2, gcx, gcy) : INF_COST;
        o.w = V3 ? cost_fast(iou_fn(P3.x, P3.y, P3.z, P3.w, gx1, gy1, gx2, gy2),
                             s_t[lab][4 * q + 3], R3.x, R3.y, rs3, gcx, gcy) : INF_COST;
        *(float4*)(trow + (size_t)m * N) = o;
    }
}

// ---------- radix helpers ----------
__device__ __forceinline__ void hist_zero(unsigned (*s_h)[257], int tid) {
    unsigned* f = &s_h[0][0];
    for (int j = tid; j < 4 * 257; j += 256) f[j] = 0;
}

__device__ __forceinline__ void hist_pick(unsigned (*s_h)[257], unsigned* s_wsum,
    unsigned* s_sel, int tid, int lane, int w, unsigned need, int infbin, unsigned infcnt)
{
    unsigned cnt = s_h[0][tid] + s_h[1][tid] + s_h[2][tid] + s_h[3][tid];
    if (tid == infbin) cnt += infcnt;
    unsigned x = cnt;
#pragma unroll
    for (int d = 1; d < 64; d <<= 1) {
        unsigned y = (unsigned)__shfl_up((int)x, d);
        if (lane >= d) x += y;
    }
    if (lane == 63) s_wsum[w] = x;
    __syncthreads();
    unsigned off = 0;
    for (int ww = 0; ww < w; ++ww) off += s_wsum[ww];
    unsigned incl = x + off;
    unsigned excl = incl - cnt;
    if (tid == 255) s_sel[2] = incl;
    if (need != 0u && excl < need && need <= incl) { s_sel[0] = (unsigned)tid; s_sel[1] = excl; }
    __syncthreads();
}

// ---------- kernel 2: selection only ----------
__global__ __launch_bounds__(256) void k_select(
    const float* __restrict__ pred_bboxes,
    const float* __restrict__ pred_scores,
    const float* __restrict__ tsc,
    const float* __restrict__ priors,
    const int*   __restrict__ gt_labels,
    const float* __restrict__ gt_bboxes,
    const float* __restrict__ pad,
    const unsigned char* __restrict__ valid,
    float* __restrict__ cK, int* __restrict__ nK,
    int use_t)
{
    __shared__ float    s_val[N];
    __shared__ unsigned s_h[4][257];
    __shared__ unsigned s_wsum[4];
    __shared__ unsigned s_sel[4];
    __shared__ float    s_coll[16];
    __shared__ unsigned s_cnt;
    __shared__ unsigned s_infcnt;

    const int bm = blockIdx.x;           // plain: round-robin spreads valid columns
    if (pad[bm] == 0.0f) return;

    const int b = bm / M;
    const int tid = threadIdx.x;
    const int lane = tid & 63;
    const int w = tid >> 6;

    const float4 g = ((const float4*)gt_bboxes)[bm];
    const float gx1 = g.x, gy1 = g.y, gx2 = g.z, gy2 = g.w;
    const float gcx = (gx1 + gx2) * 0.5f, gcy = (gy1 + gy2) * 0.5f;
    const int label = gt_labels[bm];
    const float4* pb4 = ((const float4*)pred_bboxes) + (size_t)b * N;

    float myv[NJ];

    // ======== pass A: iou (bit-exact) + radix for 13th-largest ========
    hist_zero(s_h, tid);
    if (tid == 0) s_cnt = 0;
    __syncthreads();
#pragma unroll
    for (int j = 0; j < NJ; ++j) {
        int n = tid + (j << 8);
        float v = 0.0f;
        if (n < N) {
            float4 p = pb4[n];
            v = iou_fn(p.x, p.y, p.z, p.w, gx1, gy1, gx2, gy2);
            unsigned bits = __float_as_uint(v);
            if (bits) atomicAdd(&s_h[tid & 3][bits >> 24], 1u);
        }
        myv[j] = v;
    }
    __syncthreads();

    hist_pick(s_h, s_wsum, s_sel, tid, lane, w, 0u, -1, 0u);
    const unsigned total = s_sel[2];
    unsigned thr_i = 0;
    if (total >= 13u) {
        unsigned pref = 0, mask = 0, need = total - 12u;
        for (int lev = 0; lev < 4; ++lev) {
            int shift = 24 - 8 * lev;
            if (lev) {
                hist_zero(s_h, tid);
                __syncthreads();
#pragma unroll
                for (int j = 0; j < NJ; ++j) {
                    unsigned bits = __float_as_uint(myv[j]);
                    if (bits && (bits & mask) == pref)
                        atomicAdd(&s_h[tid & 3][(bits >> shift) & 255u], 1u);
                }
                __syncthreads();
            }
            hist_pick(s_h, s_wsum, s_sel, tid, lane, w, need, -1, 0u);
            pref |= s_sel[0] << shift;
            mask |= 0xFFu << shift;
            need -= s_sel[1];
        }
        thr_i = pref;
    }
#pragma unroll
    for (int j = 0; j < NJ; ++j) {
        unsigned bits = __float_as_uint(myv[j]);
        if (bits > thr_i) {
            unsigned p = atomicAdd(&s_cnt, 1u);
            if (p < 16u) s_coll[p] = myv[j];
        }
    }
    __syncthreads();
    if (tid == 0) {
        int cg = (int)s_cnt; if (cg > 13) cg = 13;
        for (int a = 1; a < cg; ++a) {
            float key = s_coll[a]; int bp = a - 1;
            while (bp >= 0 && s_coll[bp] < key) { s_coll[bp + 1] = s_coll[bp]; --bp; }
            s_coll[bp + 1] = key;
        }
        float ss = 0.0f;
        for (int a = 0; a < cg; ++a) ss += s_coll[a];     // descending-order sum
        if (total >= 13u) {
            float thr = __uint_as_float(thr_i);
            for (int a = cg; a < 13; ++a) ss += thr;
        }
        int KK = (int)ss;
        if (KK < 1) KK = 1;
        s_sel[3] = (unsigned)KK;
    }

    // ======== pass B: cost (stored or fallback) + radix for K-th (cost,n) ========
    hist_zero(s_h, tid);
    if (tid == 0) s_infcnt = 0;
    __syncthreads();
    const unsigned INFB = __float_as_uint(INF_COST);
    const float* tcol = tsc + (size_t)bm * N;
    const float* srow = pred_scores + (size_t)b * N * C;
    const unsigned char* vrow = valid + (size_t)b * N;
    const float4* pr4 = (const float4*)priors;
    unsigned cInf = 0;
    if (use_t) {
#pragma unroll
        for (int j = 0; j < NJ; ++j) {
            int n = tid + (j << 8);
            float c = 0.0f;
            if (n < N) {
                c = tcol[n];
                s_val[n] = c;
                unsigned bits = __float_as_uint(c);
                if (bits == INFB) cInf++;
                else atomicAdd(&s_h[tid & 3][bits >> 24], 1u);
            }
            myv[j] = c;
        }
    } else {
#pragma unroll
        for (int j = 0; j < NJ; ++j) {
            int n = tid + (j << 8);
            float c = 0.0f;
            if (n < N) {
                if (vrow[n]) {
                    float logit = srow[(size_t)n * C + label];
                    float4 pr = pr4[n];
                    c = cost_fast(myv[j], logit, pr.x, pr.y,
                                  __builtin_amdgcn_rcpf(pr.z), gcx, gcy);
                } else c = INF_COST;
                s_val[n] = c;
                unsigned bits = __float_as_uint(c);
                if (bits == INFB) cInf++;
                else atomicAdd(&s_h[tid & 3][bits >> 24], 1u);
            }
            myv[j] = c;
        }
    }
#pragma unroll
    for (int d = 1; d < 64; d <<= 1) cInf += (unsigned)__shfl_xor((int)cInf, d);
    if (lane == 0 && cInf) atomicAdd(&s_infcnt, cInf);
    __syncthreads();
    const unsigned nInf = s_infcnt;
    const unsigned K = s_sel[3];

    unsigned pref = 0, mask = 0, need = K;
    for (int lev = 0; lev < 4; ++lev) {
        int shift = 24 - 8 * lev;
        if (lev) {
            hist_zero(s_h, tid);
            __syncthreads();
#pragma unroll
            for (int j = 0; j < NJ; ++j) {
                unsigned bits = __float_as_uint(myv[j]);
                if (bits && bits != INFB && (bits & mask) == pref)
                    atomicAdd(&s_h[tid & 3][(bits >> shift) & 255u], 1u);
            }
            __syncthreads();
        }
        int infbin = ((INFB & mask) == pref) ? (int)((INFB >> shift) & 255u) : -1;
        hist_pick(s_h, s_wsum, s_sel, tid, lane, w, need, infbin, nInf);
        pref |= s_sel[0] << shift;
        mask |= 0xFFu << shift;
        need -= s_sel[1];
    }
    {
        const int lo = tid * 33;
        const int hi = (lo + 33 < N) ? (lo + 33) : N;
        unsigned cnt = 0;
        for (int n = lo; n < hi; ++n) cnt += (__float_as_uint(s_val[n]) == pref) ? 1u : 0u;
        unsigned x = cnt;
#pragma unroll
        for (int d = 1; d < 64; d <<= 1) {
            unsigned y = (unsigned)__shfl_up((int)x, d);
            if (lane >= d) x += y;
        }
        if (lane == 63) s_wsum[w] = x;
        __syncthreads();
        unsigned off = 0;
        for (int ww = 0; ww < w; ++ww) off += s_wsum[ww];
        unsigned incl = x + off, excl = incl - cnt;
        if (excl < need && need <= incl) {
            unsigned want = need - excl;
            for (int n = lo; n < hi; ++n) {
                if (__float_as_uint(s_val[n]) == pref) {
                    if (--want == 0u) { s_sel[0] = (unsigned)n; break; }
                }
            }
        }
        __syncthreads();
    }
    if (tid == 0) { cK[bm] = __uint_as_float(pref); nK[bm] = (int)s_sel[0]; }
}

// ---------- kernel 3: per-(b,n) row ----------
__global__ __launch_bounds__(256) void k_assign(
    const float* __restrict__ pred_bboxes,
    const float* __restrict__ pred_scores,
    const float* __restrict__ tsc,
    const float* __restrict__ priors,
    const int*   __restrict__ gt_labels,
    const float* __restrict__ gt_bboxes,
    const float* __restrict__ pad,
    const unsigned char* __restrict__ valid,
    const float* __restrict__ cK,
    const int*   __restrict__ nK,
    float* __restrict__ out,
    int use_t)
{
    __shared__ float s_box[M][4];
    __shared__ float s_gc[M][2];
    __shared__ float s_ck[M];
    __shared__ int   s_lab[M];
    __shared__ int   s_nk[M];
    __shared__ unsigned char s_gtv[M];

    const int cidx = blockIdx.x;
    const int b = cidx / 33;
    const int chunk = cidx % 33;
    const int n = chunk * 256 + threadIdx.x;

    if (threadIdx.x < M) {
        int m = threadIdx.x, gi = b * M + m;
        float4 g = ((const float4*)gt_bboxes)[gi];
        s_box[m][0] = g.x; s_box[m][1] = g.y; s_box[m][2] = g.z; s_box[m][3] = g.w;
        s_gc[m][0] = (g.x + g.z) * 0.5f;
        s_gc[m][1] = (g.y + g.w) * 0.5f;
        s_ck[m] = cK[gi];
        s_lab[m] = gt_labels[gi];
        s_nk[m] = nK[gi];
        s_gtv[m] = (pad[gi] > 0.0f) ? 1 : 0;
    }
    __syncthreads();
    if (n >= N) return;

    const size_t idx = (size_t)b * N + n;

    int count = 0, firstm = -1;
    float minc = INFINITY; int amin = 0;
    float firstiou = 0.0f, aminiou = 0.0f;

    if (use_t) {
        const float* tb = tsc + (size_t)b * M * N;
#pragma unroll 4
        for (int m = 0; m < M; m++) {
            float c = tb[(size_t)m * N + n];
            if (c < minc) { minc = c; amin = m; }
            float ckm = s_ck[m]; int nkm = s_nk[m];
            bool matched = s_gtv[m] && (c < ckm || (c == ckm && n <= nkm));
            if (matched) { count++; if (firstm < 0) firstm = m; }
        }
        int mstar = (count > 1) ? amin : firstm;
        float mi = 0.0f;
        if (mstar >= 0) {
            float4 p = ((const float4*)pred_bboxes)[idx];
            mi = iou_fn(p.x, p.y, p.z, p.w,
                        s_box[mstar][0], s_box[mstar][1], s_box[mstar][2], s_box[mstar][3]);
        }
        float* o_lab = out;
        float* o_w   = out + (size_t)B * N;
        float* o_box = out + (size_t)2 * B * N;
        float* o_met = out + (size_t)6 * B * N;
        o_w[idx] = 1.0f;
        if (mstar >= 0) {
            o_lab[idx] = (float)s_lab[mstar];
            o_box[idx * 4 + 0] = s_box[mstar][0];
            o_box[idx * 4 + 1] = s_box[mstar][1];
            o_box[idx * 4 + 2] = s_box[mstar][2];
            o_box[idx * 4 + 3] = s_box[mstar][3];
            o_met[idx] = mi;
        } else {
            o_lab[idx] = (float)C;
            o_box[idx * 4 + 0] = 0.0f;
            o_box[idx * 4 + 1] = 0.0f;
            o_box[idx * 4 + 2] = 0.0f;
            o_box[idx * 4 + 3] = 0.0f;
            o_met[idx] = 0.0f;
        }
        return;
    }

    // -------- fallback (use_t == 0) --------
    const float4 p = ((const float4*)pred_bboxes)[idx];
    const float4 pr = ((const float4*)priors)[n];
    const float rst = __builtin_amdgcn_rcpf(pr.z);
    const int vn = valid[idx];
    const float* scores = pred_scores + idx * C;

    for (int m = 0; m < M; m++) {
        float iou = iou_fn(p.x, p.y, p.z, p.w,
                           s_box[m][0], s_box[m][1], s_box[m][2], s_box[m][3]);
        float c;
        if (vn) {
            float logit = scores[s_lab[m]];
            c = cost_fast(iou, logit, pr.x, pr.y, rst, s_gc[m][0], s_gc[m][1]);
        } else {
            c = INF_COST;
        }
        if (c < minc) { minc = c; amin = m; aminiou = iou; }
        float ckm = s_ck[m]; int nkm = s_nk[m];
        bool matched = s_gtv[m] && (c < ckm || (c == ckm && n <= nkm));
        if (matched) { count++; if (firstm < 0) { firstm = m; firstiou = iou; } }
    }

    int mstar; float mi;
    if (count > 1)       { mstar = amin;   mi = aminiou; }
    else if (count == 1) { mstar = firstm; mi = firstiou; }
    else                 { mstar = -1;     mi = 0.0f; }

    float* o_lab = out;
    float* o_w   = out + (size_t)B * N;
    float* o_box = out + (size_t)2 * B * N;
    float* o_met = out + (size_t)6 * B * N;
    o_w[idx] = 1.0f;
    if (mstar >= 0) {
        o_lab[idx] = (float)s_lab[mstar];
        o_box[idx * 4 + 0] = s_box[mstar][0];
        o_box[idx * 4 + 1] = s_box[mstar][1];
        o_box[idx * 4 + 2] = s_box[mstar][2];
        o_box[idx * 4 + 3] = s_box[mstar][3];
        o_met[idx] = mi;
    } else {
        o_lab[idx] = (float)C;
        o_box[idx * 4 + 0] = 0.0f;
        o_box[idx * 4 + 1] = 0.0f;
        o_box[idx * 4 + 2] = 0.0f;
        o_box[idx * 4 + 3] = 0.0f;
        o_met[idx] = 0.0f;
    }
}

extern "C" void kernel_launch(void* const* d_in, const int* in_sizes, int n_in,
                              void* d_out, int out_size, void* d_ws, size_t ws_size,
                              hipStream_t stream) {
    const float* pred_bboxes = (const float*)d_in[0];
    const float* pred_scores = (const float*)d_in[1];
    const float* priors      = (const float*)d_in[2];
    const int*   gt_labels   = (const int*)d_in[3];
    const float* gt_bboxes   = (const float*)d_in[4];
    const float* pad         = (const float*)d_in[5];
    float* out = (float*)d_out;

    const size_t t_bytes = (size_t)B * M * N * sizeof(float);
    const size_t need = t_bytes + (size_t)B * N + (size_t)B * M * 8;
    const int use_t = (ws_size >= need) ? 1 : 0;

    unsigned char* ws = (unsigned char*)d_ws;
    float* tsc; unsigned char* valid; float* cKp; int* nKp;
    if (use_t) {
        tsc   = (float*)ws;
        valid = ws + t_bytes;
        cKp   = (float*)(ws + t_bytes + (size_t)B * N);
        nKp   = (int*)  (ws + t_bytes + (size_t)B * N + (size_t)B * M * 4);
    } else {
        tsc   = (float*)ws;   // never dereferenced
        valid = ws;
        cKp   = (float*)(ws + (size_t)B * N);
        nKp   = (int*)  (ws + (size_t)B * N + (size_t)B * M * 4);
    }

    k_valid<<<(B * N + 255) / 256, 256, 0, stream>>>(priors, gt_bboxes, pad, valid);
    if (use_t)
        k_cost<<<B * 132, 256, 0, stream>>>(pred_scores, gt_labels, pred_bboxes, priors,
                                            gt_bboxes, valid, tsc);
    k_select<<<B * M, 256, 0, stream>>>(pred_bboxes, pred_scores, tsc, priors, gt_labels,
                                        gt_bboxes, pad, valid, cKp, nKp, use_t);
    k_assign<<<33 * B, 256, 0, stream>>>(pred_bboxes, pred_scores, tsc, priors, gt_labels,
                                         gt_bboxes, pad, valid, cKp, nKp, out, use_t);
}